// Round 6
// baseline (176.559 us; speedup 1.0000x reference)
//
#include <hip/hip_runtime.h>
#include <cstddef>
#include <cstdint>

#define BN_EPS 1e-5f

typedef __attribute__((ext_vector_type(8))) __bf16 bf16x8;
typedef __attribute__((ext_vector_type(4))) float f32x4;

__device__ inline unsigned short f2bf(float f) {
    unsigned u = __builtin_bit_cast(unsigned, f);
    unsigned r = (u + 0x7fff + ((u >> 16) & 1)) >> 16;
    return (unsigned short)r;
}
__device__ inline float bf2f(unsigned short u) {
    return __builtin_bit_cast(float, (unsigned)u << 16);
}

#define GLDS16(g, l)                                                        \
    __builtin_amdgcn_global_load_lds(                                       \
        (const __attribute__((address_space(1))) void*)(g),                 \
        (__attribute__((address_space(3))) void*)(l), 16, 0, 0)

// ===========================================================================
// Prep kernel: coalesced NCHW f32 -> NHWC bf16 (search + kernel) + weights.
// Block ranges: [0,G31) nhwc31, [G31,G31+G7) nhwc7, rest weights.
// ===========================================================================
template<int H, int W, int WP>
__device__ inline void nhwc_body(int bh, const float* __restrict__ in,
                                 unsigned short* __restrict__ out)
{
    __shared__ unsigned short tl[256][WP];
    const int tid = threadIdx.x;
    const int b = bh / H, h = bh - b * H;
    const int g = tid >> 5, wl = tid & 31;
    const float* base = in + (size_t)b * 256 * (H * W) + (size_t)h * W;
    if (wl < W) {
        #pragma unroll
        for (int cc = 0; cc < 32; ++cc) {
            const int c = cc * 8 + g;
            tl[c][wl] = f2bf(base[(size_t)c * (H * W) + wl]);
        }
    }
    __syncthreads();
    unsigned short* dst = out + (size_t)bh * W * 256 + tid;
    #pragma unroll
    for (int w = 0; w < W; ++w) dst[w * 256] = tl[tid][w];
}

__global__ __launch_bounds__(256)
void prep_kernel(const float* __restrict__ srch, const float* __restrict__ kin,
                 const float* __restrict__ cs_w, const float* __restrict__ ck_w,
                 const float* __restrict__ h1_w, const float* __restrict__ h2_w,
                 unsigned short* __restrict__ s16, unsigned short* __restrict__ k16,
                 unsigned short* __restrict__ wTs, unsigned short* __restrict__ wTk,
                 unsigned short* __restrict__ h1w16, unsigned short* __restrict__ h2w16,
                 int G31, int G7)
{
    const int bid = blockIdx.x;
    if (bid < G31) {
        nhwc_body<31, 31, 33>(bid, srch, s16);
    } else if (bid < G31 + G7) {
        nhwc_body<7, 7, 9>(bid - G31, kin, k16);
    } else {
        const int i = (bid - G31 - G7) * 256 + threadIdx.x;
        if (i < 589824) {
            const int ic = i & 255, t = i >> 8, oc = t & 255, khkw = t >> 8;
            wTs[i] = f2bf(cs_w[(size_t)((oc << 8) + ic) * 9 + khkw]);
        } else if (i < 1179648) {
            const int j = i - 589824;
            const int ic = j & 255, t = j >> 8, oc = t & 255, khkw = t >> 8;
            wTk[j] = f2bf(ck_w[(size_t)((oc << 8) + ic) * 9 + khkw]);
        } else if (i < 1245184) {
            const int j = i - 1179648;
            h1w16[j] = f2bf(h1_w[j]);
        } else if (i < 1249280) {
            const int j = i - 1245184;
            const int oc = j >> 8, ic = j & 255;
            h2w16[j] = (oc < 10) ? f2bf(h2_w[oc * 256 + ic]) : (unsigned short)0;
        }
    }
}

// ===========================================================================
// Combined 3x3 MFMA conv + BN + ReLU for BOTH branches (round-4 proven
// structure; epilogue now writes NHWC bf16 [pos][256] via the round-3-proven
// OUT_NT path). Blocks [0,Gs): search (XCD chunk swizzle + oct pairing);
// [Gs,Gs+Gk): kernel branch.
// ===========================================================================
struct ConvParams {
    const unsigned short* bsrc;   // NHWC bf16 [B*IH*IW][256]
    const unsigned short* wT;     // bf16 [9][256 oc][256 ic]
    const float *bg, *bb, *bm, *bv;
    unsigned short* out;          // NHWC bf16 [pos][256]
    int IH, IW, OW, PPB, N;
};

__global__ __launch_bounds__(256)
void conv3x3_kernel(ConvParams S, ConvParams K, int Gs)
{
    __shared__ __align__(16) unsigned short Alds[128 * 64];
    __shared__ __align__(16) unsigned short Blds[128 * 64];

    const int tid  = threadIdx.x;
    const int lane = tid & 63;
    const int wid  = tid >> 6;

    const int raw = blockIdx.x;
    ConvParams P;
    int tileid;
    if (raw < Gs) {
        P = S;
        const int q8 = Gs >> 3, r8 = Gs & 7;
        const int xcd = raw & 7, seq = raw >> 3;
        tileid = (xcd < r8 ? xcd * (q8 + 1) : r8 * (q8 + 1) + (xcd - r8) * q8) + seq;
    } else {
        P = K;
        tileid = raw - Gs;
    }
    const int pt  = tileid >> 1;
    const int oct = tileid & 1;
    const int oc0 = oct << 7;
    const int p0  = pt << 7;

    int aoff[4], brow[4], bgs8[4], ldsrow[4];
    #pragma unroll
    for (int i = 0; i < 4; ++i) {
        const int r  = i * 32 + wid * 8 + (lane >> 3);
        const int gs = (lane & 7) ^ (r & 7);
        aoff[i] = (oc0 + r) * 256 + gs * 8;
        int pg = p0 + r; if (pg > P.N - 1) pg = P.N - 1;
        const int bb_ = pg / P.PPB;
        const int p   = pg - bb_ * P.PPB;
        const int oh  = p / P.OW, ow = p - oh * P.OW;
        brow[i] = (bb_ * P.IH + oh) * P.IW + ow;
        bgs8[i] = gs * 8;
        ldsrow[i] = (i * 32 + wid * 8) * 64;
    }

    const int q_  = lane >> 4;
    const int lr  = lane & 15;
    const int wm0 = (wid >> 1) * 64;
    const int wn0 = (wid & 1) * 64;
    const int g0  = q_ ^ (lane & 7);
    const int g1  = (4 + q_) ^ (lane & 7);
    const unsigned short* Abase = &Alds[(wm0 + lr) * 64];
    const unsigned short* Bbase = &Blds[(wn0 + lr) * 64];

    f32x4 acc[4][4] = {};

    int kh = 0, kw = 0;
    for (int khkw = 0; khkw < 9; ++khkw) {
        const size_t wslice = (size_t)khkw << 16;
        const int tapadd = kh * P.IW + kw;
        for (int ics = 0; ics < 4; ++ics) {
            const int ic0 = ics * 64;
            __syncthreads();
            #pragma unroll
            for (int i = 0; i < 4; ++i) {
                GLDS16(P.wT + wslice + aoff[i] + ic0, &Alds[ldsrow[i]]);
                GLDS16(P.bsrc + (size_t)(brow[i] + tapadd) * 256 + ic0 + bgs8[i],
                       &Blds[ldsrow[i]]);
            }
            __syncthreads();

            bf16x8 bfr[4][2];
            #pragma unroll
            for (int n = 0; n < 4; ++n) {
                bfr[n][0] = *(const bf16x8*)(Bbase + n * 1024 + g0 * 8);
                bfr[n][1] = *(const bf16x8*)(Bbase + n * 1024 + g1 * 8);
            }
            #pragma unroll
            for (int m = 0; m < 4; ++m) {
                bf16x8 a0 = *(const bf16x8*)(Abase + m * 1024 + g0 * 8);
                bf16x8 a1 = *(const bf16x8*)(Abase + m * 1024 + g1 * 8);
                #pragma unroll
                for (int n = 0; n < 4; ++n) {
                    acc[m][n] = __builtin_amdgcn_mfma_f32_16x16x32_bf16(
                                    a0, bfr[n][0], acc[m][n], 0, 0, 0);
                    acc[m][n] = __builtin_amdgcn_mfma_f32_16x16x32_bf16(
                                    a1, bfr[n][1], acc[m][n], 0, 0, 0);
                }
            }
        }
        if (++kw == 3) { kw = 0; ++kh; }
    }

    // ---- epilogue: BN + ReLU -> NHWC bf16 [pos][256] ----
    #pragma unroll
    for (int m = 0; m < 4; ++m) {
        const int ocm = oc0 + wm0 + m * 16 + q_ * 4;
        float sc[4], sh[4];
        #pragma unroll
        for (int r = 0; r < 4; ++r) {
            sc[r] = P.bg[ocm + r] * rsqrtf(P.bv[ocm + r] + BN_EPS);
            sh[r] = P.bb[ocm + r] - P.bm[ocm + r] * sc[r];
        }
        #pragma unroll
        for (int n = 0; n < 4; ++n) {
            const int pg = p0 + wn0 + n * 16 + lr;
            if (pg < P.N) {
                unsigned e0 = f2bf(fmaxf(acc[m][n][0] * sc[0] + sh[0], 0.f));
                unsigned e1 = f2bf(fmaxf(acc[m][n][1] * sc[1] + sh[1], 0.f));
                unsigned e2 = f2bf(fmaxf(acc[m][n][2] * sc[2] + sh[2], 0.f));
                unsigned e3 = f2bf(fmaxf(acc[m][n][3] * sc[3] + sh[3], 0.f));
                uint2 v; v.x = e0 | (e1 << 16); v.y = e2 | (e3 << 16);
                *(uint2*)(P.out + (size_t)pg * 256 + ocm) = v;
            }
        }
    }
}

// ===========================================================================
// NHWC depthwise xcorr: sfeat [b*841][256] (x) kfeat [b*25][256]
//   -> xc2 [b*625+p][256] bf16.  block=(b,oh), thread=c. Sliding window,
// 25 f32 accumulators, every load coalesced across c, data L2-resident.
// ===========================================================================
__global__ __launch_bounds__(256)
void xcorr_nhwc_kernel(const unsigned short* __restrict__ sfeat,
                       const unsigned short* __restrict__ kfeat,
                       unsigned short* __restrict__ xc2)
{
    const int bid = blockIdx.x;          // b*25 + oh
    const int b = bid / 25, oh = bid - b * 25;
    const int c = threadIdx.x;

    float kv[25];
    const unsigned short* kp = kfeat + (size_t)b * 25 * 256 + c;
    #pragma unroll
    for (int t = 0; t < 25; ++t) kv[t] = bf2f(kp[t * 256]);

    float acc[25];
    #pragma unroll
    for (int ow = 0; ow < 25; ++ow) acc[ow] = 0.f;

    const unsigned short* sp = sfeat + ((size_t)(b * 29 + oh)) * 29 * 256 + c;
    #pragma unroll
    for (int i = 0; i < 5; ++i) {
        #pragma unroll
        for (int w = 0; w < 29; ++w) {
            const float sv = bf2f(sp[(i * 29 + w) * 256]);
            #pragma unroll
            for (int j = 0; j < 5; ++j) {
                if (j <= w && w - j <= 24)
                    acc[w - j] += sv * kv[i * 5 + j];
            }
        }
    }

    unsigned short* op = xc2 + ((size_t)(b * 625 + oh * 25)) * 256 + c;
    #pragma unroll
    for (int ow = 0; ow < 25; ++ow) op[ow * 256] = f2bf(acc[ow]);
}

// ===========================================================================
// head1 1x1 conv + BN + ReLU (round-3 proven 128^2 template, OUT_NT path)
// ===========================================================================
template<int KH, int KW, int IH, int IW, int OW, int PPB, bool OUT_NT>
__global__ __launch_bounds__(256)
void conv_mfma_kernel(const unsigned short* __restrict__ bsrc,
                      const unsigned short* __restrict__ wT,
                      const float* __restrict__ bn_g,
                      const float* __restrict__ bn_b,
                      const float* __restrict__ bn_m,
                      const float* __restrict__ bn_v,
                      float* __restrict__ out_f32,
                      unsigned short* __restrict__ out_nt,
                      int N)
{
    constexpr int KHW = KH * KW;
    __shared__ __align__(16) unsigned short Alds[128 * 64];
    __shared__ __align__(16) unsigned short Blds[128 * 64];

    const int tid  = threadIdx.x;
    const int lane = tid & 63;
    const int wid  = tid >> 6;

    const int NPT = (N + 127) >> 7;
    const int bid = blockIdx.x;
    const int pt  = bid % NPT;
    const int oct = bid / NPT;
    const int oc0 = oct * 128;
    const int p0  = pt * 128;

    int aoff[4], brow[4], bgs8[4], ldsrow[4];
    #pragma unroll
    for (int i = 0; i < 4; ++i) {
        const int r  = i * 32 + wid * 8 + (lane >> 3);
        const int gsv = (lane & 7) ^ (r & 7);
        aoff[i] = (oc0 + r) * 256 + gsv * 8;
        int pg = p0 + r; if (pg > N - 1) pg = N - 1;
        const int bb = pg / PPB;
        const int p  = pg - bb * PPB;
        const int oh = p / OW, ow = p - oh * OW;
        brow[i] = (bb * IH + oh) * IW + ow;
        bgs8[i] = gsv * 8;
        ldsrow[i] = (i * 32 + wid * 8) * 64;
    }

    const int q   = lane >> 4;
    const int lr  = lane & 15;
    const int wm0 = (wid >> 1) * 64;
    const int wn0 = (wid & 1) * 64;
    const int g0  = q ^ (lane & 7);
    const int g1  = (4 + q) ^ (lane & 7);
    const unsigned short* Abase = &Alds[(wm0 + lr) * 64];
    const unsigned short* Bbase = &Blds[(wn0 + lr) * 64];

    f32x4 acc[4][4] = {};

    for (int khkw = 0; khkw < KHW; ++khkw) {
        const int kh = khkw / KW;
        const int kw = khkw - kh * KW;
        const size_t wslice = (size_t)khkw * 65536;
        const int tapadd = kh * IW + kw;
        for (int ics = 0; ics < 4; ++ics) {
            const int ic0 = ics * 64;
            __syncthreads();
            #pragma unroll
            for (int i = 0; i < 4; ++i) {
                GLDS16(wT + wslice + aoff[i] + ic0, &Alds[ldsrow[i]]);
                GLDS16(bsrc + (size_t)(brow[i] + tapadd) * 256 + ic0 + bgs8[i],
                       &Blds[ldsrow[i]]);
            }
            __syncthreads();

            bf16x8 bfr[4][2];
            #pragma unroll
            for (int n = 0; n < 4; ++n) {
                bfr[n][0] = *(const bf16x8*)(Bbase + n * 1024 + g0 * 8);
                bfr[n][1] = *(const bf16x8*)(Bbase + n * 1024 + g1 * 8);
            }
            #pragma unroll
            for (int m = 0; m < 4; ++m) {
                bf16x8 a0 = *(const bf16x8*)(Abase + m * 1024 + g0 * 8);
                bf16x8 a1 = *(const bf16x8*)(Abase + m * 1024 + g1 * 8);
                #pragma unroll
                for (int n = 0; n < 4; ++n) {
                    acc[m][n] = __builtin_amdgcn_mfma_f32_16x16x32_bf16(
                                    a0, bfr[n][0], acc[m][n], 0, 0, 0);
                    acc[m][n] = __builtin_amdgcn_mfma_f32_16x16x32_bf16(
                                    a1, bfr[n][1], acc[m][n], 0, 0, 0);
                }
            }
        }
    }

    #pragma unroll
    for (int m = 0; m < 4; ++m) {
        const int ocm = oc0 + wm0 + m * 16 + q * 4;
        float sc[4], sh[4];
        #pragma unroll
        for (int r = 0; r < 4; ++r) {
            sc[r] = bn_g[ocm + r] * rsqrtf(bn_v[ocm + r] + BN_EPS);
            sh[r] = bn_b[ocm + r] - bn_m[ocm + r] * sc[r];
        }
        #pragma unroll
        for (int n = 0; n < 4; ++n) {
            const int pg = p0 + wn0 + n * 16 + lr;
            if (pg < N) {
                if (OUT_NT) {
                    unsigned e0 = f2bf(fmaxf(acc[m][n][0] * sc[0] + sh[0], 0.f));
                    unsigned e1 = f2bf(fmaxf(acc[m][n][1] * sc[1] + sh[1], 0.f));
                    unsigned e2 = f2bf(fmaxf(acc[m][n][2] * sc[2] + sh[2], 0.f));
                    unsigned e3 = f2bf(fmaxf(acc[m][n][3] * sc[3] + sh[3], 0.f));
                    uint2 v; v.x = e0 | (e1 << 16); v.y = e2 | (e3 << 16);
                    *(uint2*)(out_nt + (size_t)pg * 256 + ocm) = v;
                } else {
                    const int bb = pg / PPB;
                    const int p  = pg - bb * PPB;
                    #pragma unroll
                    for (int r = 0; r < 4; ++r)
                        out_f32[((size_t)(bb * 256 + ocm + r)) * PPB + p] =
                            fmaxf(acc[m][n][r] * sc[r] + sh[r], 0.f);
                }
            }
        }
    }
}

// ===========================================================================
// head2 MFMA projection (unchanged)
// ===========================================================================
__global__ __launch_bounds__(256)
void head2_mfma_kernel(const unsigned short* __restrict__ y,
                       const unsigned short* __restrict__ h2w16,
                       const float* __restrict__ h2b,
                       float* __restrict__ out, int N)
{
    const int tid = threadIdx.x, lane = tid & 63, wid = tid >> 6;
    const int pbase = blockIdx.x * 256 + wid * 64;
    const int q = lane >> 4, lr = lane & 15;

    const unsigned short* arow = h2w16 + lr * 256 + q * 8;
    const unsigned short* yrow[4];
    #pragma unroll
    for (int n = 0; n < 4; ++n) {
        int pg = pbase + n * 16 + lr; if (pg > N - 1) pg = N - 1;
        yrow[n] = y + (size_t)pg * 256 + q * 8;
    }

    f32x4 acc[4] = {};
    #pragma unroll
    for (int ks = 0; ks < 8; ++ks) {
        bf16x8 a = *(const bf16x8*)(arow + ks * 32);
        #pragma unroll
        for (int n = 0; n < 4; ++n) {
            bf16x8 bb = *(const bf16x8*)(yrow[n] + ks * 32);
            acc[n] = __builtin_amdgcn_mfma_f32_16x16x32_bf16(a, bb, acc[n], 0, 0, 0);
        }
    }

    #pragma unroll
    for (int n = 0; n < 4; ++n) {
        const int pg = pbase + n * 16 + lr;
        if (pg < N) {
            const int b = pg / 625, p = pg - b * 625;
            #pragma unroll
            for (int r = 0; r < 4; ++r) {
                const int oc = q * 4 + r;
                if (oc < 10)
                    out[((size_t)(b * 10 + oc)) * 625 + p] = acc[n][r] + h2b[oc];
            }
        }
    }
}

// ===========================================================================
extern "C" void kernel_launch(void* const* d_in, const int* in_sizes, int n_in,
                              void* d_out, int out_size, void* d_ws, size_t ws_size,
                              hipStream_t stream)
{
    const float* kin  = (const float*)d_in[0];
    const float* srch = (const float*)d_in[1];
    const float* ck_w = (const float*)d_in[2];
    const float* ck_g = (const float*)d_in[3];
    const float* ck_b = (const float*)d_in[4];
    const float* ck_m = (const float*)d_in[5];
    const float* ck_v = (const float*)d_in[6];
    const float* cs_w = (const float*)d_in[7];
    const float* cs_g = (const float*)d_in[8];
    const float* cs_b = (const float*)d_in[9];
    const float* cs_m = (const float*)d_in[10];
    const float* cs_v = (const float*)d_in[11];
    const float* h1_w = (const float*)d_in[12];
    const float* h_g  = (const float*)d_in[13];
    const float* h_b  = (const float*)d_in[14];
    const float* h_m  = (const float*)d_in[15];
    const float* h_v  = (const float*)d_in[16];
    const float* h2_w = (const float*)d_in[17];
    const float* h2_b = (const float*)d_in[18];

    const int B = in_sizes[0] / (256 * 7 * 7);   // 64

    // ---- workspace layout (lifetime-aliased, ~64 MB) ----
    uint8_t* w = (uint8_t*)d_ws;
    unsigned short* s16     = (unsigned short*)(w);             // B*31*31*256 bf16 (31.5MB)
    unsigned short* xc2     = (unsigned short*)(w);             // 40000*256 bf16, aliases s16
    unsigned short* sfeat16 = (unsigned short*)(w + 31490048);  // B*841*256 bf16 (27.6MB)
    unsigned short* y       = (unsigned short*)(w + 31490048);  // aliases sfeat16
    unsigned short* kf16    = (unsigned short*)(w + 59047936);  // B*25*256 bf16
    unsigned short* k16     = (unsigned short*)(w + 59867136);  // B*7*7*256 bf16
    unsigned short* wTk     = (unsigned short*)(w + 61472768);
    unsigned short* wTs     = (unsigned short*)(w + 62652416);
    unsigned short* h1w16   = (unsigned short*)(w + 63832064);
    unsigned short* h2w16   = (unsigned short*)(w + 63963136);

    const int Ns = B * 841;    // 53824
    const int Nk = B * 25;     // 1600
    const int Nh = B * 625;    // 40000
    const int Gs = 2 * ((Ns + 127) / 128);   // 842
    const int Gk = 2 * ((Nk + 127) / 128);   // 26
    const int G31 = B * 31, G7 = B * 7;

    dim3 blk(256, 1, 1);

    // 1) prep: coalesced NHWC transforms + weight conversions
    hipLaunchKernelGGL(prep_kernel, dim3(G31 + G7 + 4880), blk, 0, stream,
                       srch, kin, cs_w, ck_w, h1_w, h2_w,
                       s16, k16, wTs, wTk, h1w16, h2w16, G31, G7);

    // 2) both 3x3 convs (round-4 structure), NHWC bf16 outputs
    ConvParams S{ s16, wTs, cs_g, cs_b, cs_m, cs_v, sfeat16, 31, 31, 29, 841, Ns };
    ConvParams K{ k16, wTk, ck_g, ck_b, ck_m, ck_v, kf16, 7, 7, 5, 25, Nk };
    hipLaunchKernelGGL(conv3x3_kernel, dim3(Gs + Gk), blk, 0, stream, S, K, Gs);

    // 3) NHWC depthwise xcorr -> xc2 bf16 [pos][256]
    hipLaunchKernelGGL(xcorr_nhwc_kernel, dim3(B * 25), blk, 0, stream,
                       sfeat16, kf16, xc2);

    // 4) head1 1x1 conv + BN + ReLU -> y bf16 [pos][256]
    hipLaunchKernelGGL((conv_mfma_kernel<1, 1, 25, 25, 25, 625, true>),
                       dim3(2 * ((Nh + 127) / 128)), blk, 0, stream,
                       xc2, h1w16, h_g, h_b, h_m, h_v, (float*)nullptr, y, Nh);

    // 5) head2 projection + bias
    hipLaunchKernelGGL(head2_mfma_kernel, dim3((Nh + 255) / 256), blk, 0, stream,
                       y, h2w16, h2_b, (float*)d_out, Nh);
}

// Round 7
// 166.600 us; speedup vs baseline: 1.0598x; 1.0598x over previous
//
#include <hip/hip_runtime.h>
#include <cstddef>
#include <cstdint>

#define BN_EPS 1e-5f

typedef __attribute__((ext_vector_type(8))) __bf16 bf16x8;
typedef __attribute__((ext_vector_type(4))) float f32x4;

__device__ inline unsigned short f2bf(float f) {
    unsigned u = __builtin_bit_cast(unsigned, f);
    unsigned r = (u + 0x7fff + ((u >> 16) & 1)) >> 16;
    return (unsigned short)r;
}
__device__ inline float bf2f(unsigned short u) {
    return __builtin_bit_cast(float, (unsigned)u << 16);
}

#define GLDS16(g, l)                                                        \
    __builtin_amdgcn_global_load_lds(                                       \
        (const __attribute__((address_space(1))) void*)(g),                 \
        (__attribute__((address_space(3))) void*)(l), 16, 0, 0)

// ===========================================================================
// Prep kernel: coalesced NCHW f32 -> NHWC bf16 (search + kernel) + weights.
// ===========================================================================
template<int H, int W, int WP>
__device__ inline void nhwc_body(int bh, const float* __restrict__ in,
                                 unsigned short* __restrict__ out)
{
    __shared__ unsigned short tl[256][WP];
    const int tid = threadIdx.x;
    const int b = bh / H, h = bh - b * H;
    const int g = tid >> 5, wl = tid & 31;
    const float* base = in + (size_t)b * 256 * (H * W) + (size_t)h * W;
    if (wl < W) {
        #pragma unroll
        for (int cc = 0; cc < 32; ++cc) {
            const int c = cc * 8 + g;
            tl[c][wl] = f2bf(base[(size_t)c * (H * W) + wl]);
        }
    }
    __syncthreads();
    unsigned short* dst = out + (size_t)bh * W * 256 + tid;
    #pragma unroll
    for (int w = 0; w < W; ++w) dst[w * 256] = tl[tid][w];
}

__global__ __launch_bounds__(256)
void prep_kernel(const float* __restrict__ srch, const float* __restrict__ kin,
                 const float* __restrict__ cs_w, const float* __restrict__ ck_w,
                 const float* __restrict__ h1_w, const float* __restrict__ h2_w,
                 unsigned short* __restrict__ s16, unsigned short* __restrict__ k16,
                 unsigned short* __restrict__ wTs, unsigned short* __restrict__ wTk,
                 unsigned short* __restrict__ h1w16, unsigned short* __restrict__ h2w16,
                 int G31, int G7)
{
    const int bid = blockIdx.x;
    if (bid < G31) {
        nhwc_body<31, 31, 33>(bid, srch, s16);
    } else if (bid < G31 + G7) {
        nhwc_body<7, 7, 9>(bid - G31, kin, k16);
    } else {
        const int i = (bid - G31 - G7) * 256 + threadIdx.x;
        if (i < 589824) {
            const int ic = i & 255, t = i >> 8, oc = t & 255, khkw = t >> 8;
            wTs[i] = f2bf(cs_w[(size_t)((oc << 8) + ic) * 9 + khkw]);
        } else if (i < 1179648) {
            const int j = i - 589824;
            const int ic = j & 255, t = j >> 8, oc = t & 255, khkw = t >> 8;
            wTk[j] = f2bf(ck_w[(size_t)((oc << 8) + ic) * 9 + khkw]);
        } else if (i < 1245184) {
            const int j = i - 1179648;
            h1w16[j] = f2bf(h1_w[j]);
        } else if (i < 1249280) {
            const int j = i - 1245184;
            const int oc = j >> 8, ic = j & 255;
            h2w16[j] = (oc < 10) ? f2bf(h2_w[oc * 256 + ic]) : (unsigned short)0;
        }
    }
}

// ===========================================================================
// Combined 3x3 MFMA conv + BN + ReLU for BOTH branches (round-6 proven,
// unchanged). NHWC bf16 output.
// ===========================================================================
struct ConvParams {
    const unsigned short* bsrc;
    const unsigned short* wT;
    const float *bg, *bb, *bm, *bv;
    unsigned short* out;          // NHWC bf16 [pos][256]
    int IH, IW, OW, PPB, N;
};

__global__ __launch_bounds__(256)
void conv3x3_kernel(ConvParams S, ConvParams K, int Gs)
{
    __shared__ __align__(16) unsigned short Alds[128 * 64];
    __shared__ __align__(16) unsigned short Blds[128 * 64];

    const int tid  = threadIdx.x;
    const int lane = tid & 63;
    const int wid  = tid >> 6;

    const int raw = blockIdx.x;
    ConvParams P;
    int tileid;
    if (raw < Gs) {
        P = S;
        const int q8 = Gs >> 3, r8 = Gs & 7;
        const int xcd = raw & 7, seq = raw >> 3;
        tileid = (xcd < r8 ? xcd * (q8 + 1) : r8 * (q8 + 1) + (xcd - r8) * q8) + seq;
    } else {
        P = K;
        tileid = raw - Gs;
    }
    const int pt  = tileid >> 1;
    const int oct = tileid & 1;
    const int oc0 = oct << 7;
    const int p0  = pt << 7;

    int aoff[4], brow[4], bgs8[4], ldsrow[4];
    #pragma unroll
    for (int i = 0; i < 4; ++i) {
        const int r  = i * 32 + wid * 8 + (lane >> 3);
        const int gs = (lane & 7) ^ (r & 7);
        aoff[i] = (oc0 + r) * 256 + gs * 8;
        int pg = p0 + r; if (pg > P.N - 1) pg = P.N - 1;
        const int bb_ = pg / P.PPB;
        const int p   = pg - bb_ * P.PPB;
        const int oh  = p / P.OW, ow = p - oh * P.OW;
        brow[i] = (bb_ * P.IH + oh) * P.IW + ow;
        bgs8[i] = gs * 8;
        ldsrow[i] = (i * 32 + wid * 8) * 64;
    }

    const int q_  = lane >> 4;
    const int lr  = lane & 15;
    const int wm0 = (wid >> 1) * 64;
    const int wn0 = (wid & 1) * 64;
    const int g0  = q_ ^ (lane & 7);
    const int g1  = (4 + q_) ^ (lane & 7);
    const unsigned short* Abase = &Alds[(wm0 + lr) * 64];
    const unsigned short* Bbase = &Blds[(wn0 + lr) * 64];

    f32x4 acc[4][4] = {};

    int kh = 0, kw = 0;
    for (int khkw = 0; khkw < 9; ++khkw) {
        const size_t wslice = (size_t)khkw << 16;
        const int tapadd = kh * P.IW + kw;
        for (int ics = 0; ics < 4; ++ics) {
            const int ic0 = ics * 64;
            __syncthreads();
            #pragma unroll
            for (int i = 0; i < 4; ++i) {
                GLDS16(P.wT + wslice + aoff[i] + ic0, &Alds[ldsrow[i]]);
                GLDS16(P.bsrc + (size_t)(brow[i] + tapadd) * 256 + ic0 + bgs8[i],
                       &Blds[ldsrow[i]]);
            }
            __syncthreads();

            bf16x8 bfr[4][2];
            #pragma unroll
            for (int n = 0; n < 4; ++n) {
                bfr[n][0] = *(const bf16x8*)(Bbase + n * 1024 + g0 * 8);
                bfr[n][1] = *(const bf16x8*)(Bbase + n * 1024 + g1 * 8);
            }
            #pragma unroll
            for (int m = 0; m < 4; ++m) {
                bf16x8 a0 = *(const bf16x8*)(Abase + m * 1024 + g0 * 8);
                bf16x8 a1 = *(const bf16x8*)(Abase + m * 1024 + g1 * 8);
                #pragma unroll
                for (int n = 0; n < 4; ++n) {
                    acc[m][n] = __builtin_amdgcn_mfma_f32_16x16x32_bf16(
                                    a0, bfr[n][0], acc[m][n], 0, 0, 0);
                    acc[m][n] = __builtin_amdgcn_mfma_f32_16x16x32_bf16(
                                    a1, bfr[n][1], acc[m][n], 0, 0, 0);
                }
            }
        }
        if (++kw == 3) { kw = 0; ++kh; }
    }

    #pragma unroll
    for (int m = 0; m < 4; ++m) {
        const int ocm = oc0 + wm0 + m * 16 + q_ * 4;
        float sc[4], sh[4];
        #pragma unroll
        for (int r = 0; r < 4; ++r) {
            sc[r] = P.bg[ocm + r] * rsqrtf(P.bv[ocm + r] + BN_EPS);
            sh[r] = P.bb[ocm + r] - P.bm[ocm + r] * sc[r];
        }
        #pragma unroll
        for (int n = 0; n < 4; ++n) {
            const int pg = p0 + wn0 + n * 16 + lr;
            if (pg < P.N) {
                unsigned e0 = f2bf(fmaxf(acc[m][n][0] * sc[0] + sh[0], 0.f));
                unsigned e1 = f2bf(fmaxf(acc[m][n][1] * sc[1] + sh[1], 0.f));
                unsigned e2 = f2bf(fmaxf(acc[m][n][2] * sc[2] + sh[2], 0.f));
                unsigned e3 = f2bf(fmaxf(acc[m][n][3] * sc[3] + sh[3], 0.f));
                uint2 v; v.x = e0 | (e1 << 16); v.y = e2 | (e3 << 16);
                *(uint2*)(P.out + (size_t)pg * 256 + ocm) = v;
            }
        }
    }
}

// ===========================================================================
// NHWC depthwise xcorr (round-6 proven, unchanged)
// ===========================================================================
__global__ __launch_bounds__(256)
void xcorr_nhwc_kernel(const unsigned short* __restrict__ sfeat,
                       const unsigned short* __restrict__ kfeat,
                       unsigned short* __restrict__ xc2)
{
    const int bid = blockIdx.x;
    const int b = bid / 25, oh = bid - b * 25;
    const int c = threadIdx.x;

    float kv[25];
    const unsigned short* kp = kfeat + (size_t)b * 25 * 256 + c;
    #pragma unroll
    for (int t = 0; t < 25; ++t) kv[t] = bf2f(kp[t * 256]);

    float acc[25];
    #pragma unroll
    for (int ow = 0; ow < 25; ++ow) acc[ow] = 0.f;

    const unsigned short* sp = sfeat + ((size_t)(b * 29 + oh)) * 29 * 256 + c;
    #pragma unroll
    for (int i = 0; i < 5; ++i) {
        #pragma unroll
        for (int w = 0; w < 29; ++w) {
            const float sv = bf2f(sp[(i * 29 + w) * 256]);
            #pragma unroll
            for (int j = 0; j < 5; ++j) {
                if (j <= w && w - j <= 24)
                    acc[w - j] += sv * kv[i * 5 + j];
            }
        }
    }

    unsigned short* op = xc2 + ((size_t)(b * 625 + oh * 25)) * 256 + c;
    #pragma unroll
    for (int ow = 0; ow < 25; ++ow) op[ow * 256] = f2bf(acc[ow]);
}

// ===========================================================================
// Fused head: (1x1 conv 256->256 + BN + ReLU) then (1x1 conv 256->10 + bias)
//   xc2  : bf16 [40000][256]
//   h1w16: bf16 [256 oc][256 ic]
//   h2w16: bf16 [16][256] (rows 10..15 zero)
//   out  : f32 [b][10][625]
// Block = 64 positions x 256 oc, 256 threads (4 waves as 2m x 2n).
// GEMM1: K=256 in 4 ic-steps (conv-proven staging + MFMA order -> y values
// bitwise-identical to round-6 head1). y tile -> LDS bf16 [64][264].
// GEMM2: head2-proven fragment pattern, B-frags from LDS y tile.
// LDS union: A[256x64]=32KB + B[64x64]=8KB  ||  Y[64][264]=33.8KB.
// grid = 40000/64 = 625 blocks (exact, no bounds checks).
// ===========================================================================
__global__ __launch_bounds__(256)
void fused_head_kernel(const unsigned short* __restrict__ xc2,
                       const unsigned short* __restrict__ h1w16,
                       const unsigned short* __restrict__ h2w16,
                       const float* __restrict__ bn_g,
                       const float* __restrict__ bn_b,
                       const float* __restrict__ bn_m,
                       const float* __restrict__ bn_v,
                       const float* __restrict__ h2b,
                       float* __restrict__ out)
{
    __shared__ __align__(16) unsigned short lds[20480];   // 40 KB
    unsigned short* Alds = lds;                            // [256][64]
    unsigned short* Blds = lds + 16384;                    // [64][64]
    unsigned short* Ylds = lds;                            // [64][264] (aliases)

    const int tid  = threadIdx.x;
    const int lane = tid & 63;
    const int wid  = tid >> 6;
    const int p0   = blockIdx.x * 64;

    // ---- staging maps ----
    const int lrow = lane >> 3;                 // 0..7
    const int gs   = 0;                         // placeholder (per-issue below)
    (void)gs;

    // A: 8 issues/wave (rows s*32 + wid*8), B: 2 issues/wave
    int aoffs[8], aldsr[8];
    #pragma unroll
    for (int s = 0; s < 8; ++s) {
        const int rowb = s * 32 + wid * 8;
        const int row  = rowb + lrow;
        const int g    = (lane & 7) ^ (row & 7);
        aoffs[s] = row * 256 + g * 8;
        aldsr[s] = rowb * 64;
    }
    int boffs[2], bldsr[2];
    #pragma unroll
    for (int t = 0; t < 2; ++t) {
        const int rowb = t * 32 + wid * 8;
        const int row  = rowb + lrow;
        const int g    = (lane & 7) ^ (row & 7);
        boffs[t] = (p0 + row) * 256 + g * 8;
        bldsr[t] = rowb * 64;
    }

    // ---- compute maps ----
    const int q_ = lane >> 4;
    const int lr = lane & 15;
    const int wm = wid >> 1;                    // 0/1 -> oc half (128)
    const int wn = wid & 1;                     // 0/1 -> pos half (32)
    const int g0 = q_ ^ (lane & 7);
    const int g1 = (4 + q_) ^ (lane & 7);
    const unsigned short* Abase = &Alds[(wm * 128 + lr) * 64];
    const unsigned short* Bbase = &Blds[(wn * 32 + lr) * 64];

    f32x4 acc[8][2] = {};

    for (int ics = 0; ics < 4; ++ics) {
        const int ic0 = ics * 64;
        __syncthreads();
        #pragma unroll
        for (int s = 0; s < 8; ++s)
            GLDS16(h1w16 + aoffs[s] + ic0, &Alds[aldsr[s]]);
        #pragma unroll
        for (int t = 0; t < 2; ++t)
            GLDS16(xc2 + boffs[t] + ic0, &Blds[bldsr[t]]);
        __syncthreads();

        bf16x8 bfr[2][2];
        #pragma unroll
        for (int n = 0; n < 2; ++n) {
            bfr[n][0] = *(const bf16x8*)(Bbase + n * 1024 + g0 * 8);
            bfr[n][1] = *(const bf16x8*)(Bbase + n * 1024 + g1 * 8);
        }
        #pragma unroll
        for (int m = 0; m < 8; ++m) {
            bf16x8 a0 = *(const bf16x8*)(Abase + m * 1024 + g0 * 8);
            bf16x8 a1 = *(const bf16x8*)(Abase + m * 1024 + g1 * 8);
            #pragma unroll
            for (int n = 0; n < 2; ++n) {
                acc[m][n] = __builtin_amdgcn_mfma_f32_16x16x32_bf16(
                                a0, bfr[n][0], acc[m][n], 0, 0, 0);
                acc[m][n] = __builtin_amdgcn_mfma_f32_16x16x32_bf16(
                                a1, bfr[n][1], acc[m][n], 0, 0, 0);
            }
        }
    }

    // ---- BN + ReLU -> Y tile in LDS (bf16, row stride 264) ----
    __syncthreads();                 // all LDS reads of A/B retired
    #pragma unroll
    for (int m = 0; m < 8; ++m) {
        const int ocm = wm * 128 + m * 16 + q_ * 4;
        float sc[4], sh[4];
        #pragma unroll
        for (int r = 0; r < 4; ++r) {
            sc[r] = bn_g[ocm + r] * rsqrtf(bn_v[ocm + r] + BN_EPS);
            sh[r] = bn_b[ocm + r] - bn_m[ocm + r] * sc[r];
        }
        #pragma unroll
        for (int n = 0; n < 2; ++n) {
            const int pl = wn * 32 + n * 16 + lr;
            unsigned e0 = f2bf(fmaxf(acc[m][n][0] * sc[0] + sh[0], 0.f));
            unsigned e1 = f2bf(fmaxf(acc[m][n][1] * sc[1] + sh[1], 0.f));
            unsigned e2 = f2bf(fmaxf(acc[m][n][2] * sc[2] + sh[2], 0.f));
            unsigned e3 = f2bf(fmaxf(acc[m][n][3] * sc[3] + sh[3], 0.f));
            uint2 v; v.x = e0 | (e1 << 16); v.y = e2 | (e3 << 16);
            *(uint2*)(Ylds + (size_t)pl * 264 + ocm) = v;
        }
    }
    __syncthreads();

    // ---- GEMM2: out[16 oc][64 pos] = h2w16(16x256) . Y^T ----
    const int pl = wid * 16 + lr;               // 0..63
    const unsigned short* arow = h2w16 + lr * 256 + q_ * 8;
    const unsigned short* brow = Ylds + (size_t)pl * 264 + q_ * 8;

    f32x4 acc2 = {};
    #pragma unroll
    for (int ks = 0; ks < 8; ++ks) {
        bf16x8 a  = *(const bf16x8*)(arow + ks * 32);
        bf16x8 bb = *(const bf16x8*)(brow + ks * 32);
        acc2 = __builtin_amdgcn_mfma_f32_16x16x32_bf16(a, bb, acc2, 0, 0, 0);
    }

    const int pg = p0 + pl;
    const int b = pg / 625, p = pg - b * 625;
    #pragma unroll
    for (int r = 0; r < 4; ++r) {
        const int oc = q_ * 4 + r;
        if (oc < 10)
            out[((size_t)(b * 10 + oc)) * 625 + p] = acc2[r] + h2b[oc];
    }
}

// ===========================================================================
extern "C" void kernel_launch(void* const* d_in, const int* in_sizes, int n_in,
                              void* d_out, int out_size, void* d_ws, size_t ws_size,
                              hipStream_t stream)
{
    const float* kin  = (const float*)d_in[0];
    const float* srch = (const float*)d_in[1];
    const float* ck_w = (const float*)d_in[2];
    const float* ck_g = (const float*)d_in[3];
    const float* ck_b = (const float*)d_in[4];
    const float* ck_m = (const float*)d_in[5];
    const float* ck_v = (const float*)d_in[6];
    const float* cs_w = (const float*)d_in[7];
    const float* cs_g = (const float*)d_in[8];
    const float* cs_b = (const float*)d_in[9];
    const float* cs_m = (const float*)d_in[10];
    const float* cs_v = (const float*)d_in[11];
    const float* h1_w = (const float*)d_in[12];
    const float* h_g  = (const float*)d_in[13];
    const float* h_b  = (const float*)d_in[14];
    const float* h_m  = (const float*)d_in[15];
    const float* h_v  = (const float*)d_in[16];
    const float* h2_w = (const float*)d_in[17];
    const float* h2_b = (const float*)d_in[18];

    const int B = in_sizes[0] / (256 * 7 * 7);   // 64

    // ---- workspace layout (lifetime-aliased) ----
    uint8_t* w = (uint8_t*)d_ws;
    unsigned short* s16     = (unsigned short*)(w);             // B*31*31*256 bf16
    unsigned short* xc2     = (unsigned short*)(w);             // 40000*256 bf16, aliases s16
    unsigned short* sfeat16 = (unsigned short*)(w + 31490048);  // B*841*256 bf16
    unsigned short* kf16    = (unsigned short*)(w + 59047936);  // B*25*256 bf16
    unsigned short* k16     = (unsigned short*)(w + 59867136);  // B*7*7*256 bf16
    unsigned short* wTk     = (unsigned short*)(w + 61472768);
    unsigned short* wTs     = (unsigned short*)(w + 62652416);
    unsigned short* h1w16   = (unsigned short*)(w + 63832064);
    unsigned short* h2w16   = (unsigned short*)(w + 63963136);

    const int Ns = B * 841;    // 53824
    const int Nk = B * 25;     // 1600
    const int Nh = B * 625;    // 40000
    const int Gs = 2 * ((Ns + 127) / 128);   // 842
    const int Gk = 2 * ((Nk + 127) / 128);   // 26
    const int G31 = B * 31, G7 = B * 7;

    dim3 blk(256, 1, 1);

    // 1) prep
    hipLaunchKernelGGL(prep_kernel, dim3(G31 + G7 + 4880), blk, 0, stream,
                       srch, kin, cs_w, ck_w, h1_w, h2_w,
                       s16, k16, wTs, wTk, h1w16, h2w16, G31, G7);

    // 2) both 3x3 convs
    ConvParams S{ s16, wTs, cs_g, cs_b, cs_m, cs_v, sfeat16, 31, 31, 29, 841, Ns };
    ConvParams K{ k16, wTk, ck_g, ck_b, ck_m, ck_v, kf16, 7, 7, 5, 25, Nk };
    hipLaunchKernelGGL(conv3x3_kernel, dim3(Gs + Gk), blk, 0, stream, S, K, Gs);

    // 3) NHWC depthwise xcorr
    hipLaunchKernelGGL(xcorr_nhwc_kernel, dim3(B * 25), blk, 0, stream,
                       sfeat16, kf16, xc2);

    // 4) fused head (1x1 conv + BN + ReLU + 1x1 conv + bias)
    hipLaunchKernelGGL(fused_head_kernel, dim3(Nh / 64), blk, 0, stream,
                       xc2, h1w16, h2w16, h_g, h_b, h_m, h_v, h2_b,
                       (float*)d_out);
}

// Round 8
// 165.327 us; speedup vs baseline: 1.0679x; 1.0077x over previous
//
#include <hip/hip_runtime.h>
#include <cstddef>
#include <cstdint>

#define BN_EPS 1e-5f

typedef __attribute__((ext_vector_type(8))) __bf16 bf16x8;
typedef __attribute__((ext_vector_type(4))) float f32x4;

__device__ inline unsigned short f2bf(float f) {
    unsigned u = __builtin_bit_cast(unsigned, f);
    unsigned r = (u + 0x7fff + ((u >> 16) & 1)) >> 16;
    return (unsigned short)r;
}
__device__ inline float bf2f(unsigned short u) {
    return __builtin_bit_cast(float, (unsigned)u << 16);
}

#define GLDS16(g, l)                                                        \
    __builtin_amdgcn_global_load_lds(                                       \
        (const __attribute__((address_space(1))) void*)(g),                 \
        (__attribute__((address_space(3))) void*)(l), 16, 0, 0)

// ===========================================================================
// Prep kernel: NCHW f32 -> NHWC bf16 as tiled per-batch transpose (coalesced
// 256B f32 reads, 128B bf16 writes) + weight conversions.
// Block ranges: [0,GS) search-transpose, [GS,GS+GK) kernel-transpose, rest wgts.
// ===========================================================================
template<int HW, int HWT>
__device__ inline void transpose_body(int rb, const float* __restrict__ in,
                                      unsigned short* __restrict__ out)
{
    __shared__ unsigned short tl[64][66];
    const int tid  = threadIdx.x;
    const int lane = tid & 63, w = tid >> 6;
    const int b  = rb / (HWT * 4);
    const int r2 = rb - b * (HWT * 4);
    const int ht = r2 >> 2, ct = r2 & 3;
    const int c0 = ct * 64, hw0 = ht * 64;
    const int hw = hw0 + lane;
    const float* ib = in + ((size_t)b * 256 + c0) * HW;
    #pragma unroll
    for (int r = 0; r < 16; ++r) {
        const int cl = w * 16 + r;
        const float v = (hw < HW) ? ib[(size_t)cl * HW + hw] : 0.f;
        tl[cl][lane] = f2bf(v);
    }
    __syncthreads();
    unsigned short* ob = out + ((size_t)b * HW + hw0) * 256 + c0 + lane;
    #pragma unroll
    for (int jj = 0; jj < 16; ++jj) {
        const int j = jj * 4 + w;
        if (hw0 + j < HW) ob[(size_t)j * 256] = tl[lane][j];
    }
}

__global__ __launch_bounds__(256)
void prep_kernel(const float* __restrict__ srch, const float* __restrict__ kin,
                 const float* __restrict__ cs_w, const float* __restrict__ ck_w,
                 const float* __restrict__ h1_w, const float* __restrict__ h2_w,
                 unsigned short* __restrict__ s16, unsigned short* __restrict__ k16,
                 unsigned short* __restrict__ wTs, unsigned short* __restrict__ wTk,
                 unsigned short* __restrict__ h1w16, unsigned short* __restrict__ h2w16,
                 int GS, int GK)
{
    const int bid = blockIdx.x;
    if (bid < GS) {
        transpose_body<961, 16>(bid, srch, s16);
    } else if (bid < GS + GK) {
        transpose_body<49, 1>(bid - GS, kin, k16);
    } else {
        const int i = (bid - GS - GK) * 256 + threadIdx.x;
        if (i < 589824) {
            const int ic = i & 255, t = i >> 8, oc = t & 255, khkw = t >> 8;
            wTs[i] = f2bf(cs_w[(size_t)((oc << 8) + ic) * 9 + khkw]);
        } else if (i < 1179648) {
            const int j = i - 589824;
            const int ic = j & 255, t = j >> 8, oc = t & 255, khkw = t >> 8;
            wTk[j] = f2bf(ck_w[(size_t)((oc << 8) + ic) * 9 + khkw]);
        } else if (i < 1245184) {
            const int j = i - 1179648;
            h1w16[j] = f2bf(h1_w[j]);
        } else if (i < 1249280) {
            const int j = i - 1245184;
            const int oc = j >> 8, ic = j & 255;
            h2w16[j] = (oc < 10) ? f2bf(h2_w[oc * 256 + ic]) : (unsigned short)0;
        }
    }
}

// ===========================================================================
// Combined 3x3 MFMA conv + BN + ReLU for BOTH branches (round-6/7 proven,
// unchanged). NHWC bf16 output.
// ===========================================================================
struct ConvParams {
    const unsigned short* bsrc;
    const unsigned short* wT;
    const float *bg, *bb, *bm, *bv;
    unsigned short* out;          // NHWC bf16 [pos][256]
    int IH, IW, OW, PPB, N;
};

__global__ __launch_bounds__(256)
void conv3x3_kernel(ConvParams S, ConvParams K, int Gs)
{
    __shared__ __align__(16) unsigned short Alds[128 * 64];
    __shared__ __align__(16) unsigned short Blds[128 * 64];

    const int tid  = threadIdx.x;
    const int lane = tid & 63;
    const int wid  = tid >> 6;

    const int raw = blockIdx.x;
    ConvParams P;
    int tileid;
    if (raw < Gs) {
        P = S;
        const int q8 = Gs >> 3, r8 = Gs & 7;
        const int xcd = raw & 7, seq = raw >> 3;
        tileid = (xcd < r8 ? xcd * (q8 + 1) : r8 * (q8 + 1) + (xcd - r8) * q8) + seq;
    } else {
        P = K;
        tileid = raw - Gs;
    }
    const int pt  = tileid >> 1;
    const int oct = tileid & 1;
    const int oc0 = oct << 7;
    const int p0  = pt << 7;

    int aoff[4], brow[4], bgs8[4], ldsrow[4];
    #pragma unroll
    for (int i = 0; i < 4; ++i) {
        const int r  = i * 32 + wid * 8 + (lane >> 3);
        const int gs = (lane & 7) ^ (r & 7);
        aoff[i] = (oc0 + r) * 256 + gs * 8;
        int pg = p0 + r; if (pg > P.N - 1) pg = P.N - 1;
        const int bb_ = pg / P.PPB;
        const int p   = pg - bb_ * P.PPB;
        const int oh  = p / P.OW, ow = p - oh * P.OW;
        brow[i] = (bb_ * P.IH + oh) * P.IW + ow;
        bgs8[i] = gs * 8;
        ldsrow[i] = (i * 32 + wid * 8) * 64;
    }

    const int q_  = lane >> 4;
    const int lr  = lane & 15;
    const int wm0 = (wid >> 1) * 64;
    const int wn0 = (wid & 1) * 64;
    const int g0  = q_ ^ (lane & 7);
    const int g1  = (4 + q_) ^ (lane & 7);
    const unsigned short* Abase = &Alds[(wm0 + lr) * 64];
    const unsigned short* Bbase = &Blds[(wn0 + lr) * 64];

    f32x4 acc[4][4] = {};

    int kh = 0, kw = 0;
    for (int khkw = 0; khkw < 9; ++khkw) {
        const size_t wslice = (size_t)khkw << 16;
        const int tapadd = kh * P.IW + kw;
        for (int ics = 0; ics < 4; ++ics) {
            const int ic0 = ics * 64;
            __syncthreads();
            #pragma unroll
            for (int i = 0; i < 4; ++i) {
                GLDS16(P.wT + wslice + aoff[i] + ic0, &Alds[ldsrow[i]]);
                GLDS16(P.bsrc + (size_t)(brow[i] + tapadd) * 256 + ic0 + bgs8[i],
                       &Blds[ldsrow[i]]);
            }
            __syncthreads();

            bf16x8 bfr[4][2];
            #pragma unroll
            for (int n = 0; n < 4; ++n) {
                bfr[n][0] = *(const bf16x8*)(Bbase + n * 1024 + g0 * 8);
                bfr[n][1] = *(const bf16x8*)(Bbase + n * 1024 + g1 * 8);
            }
            #pragma unroll
            for (int m = 0; m < 4; ++m) {
                bf16x8 a0 = *(const bf16x8*)(Abase + m * 1024 + g0 * 8);
                bf16x8 a1 = *(const bf16x8*)(Abase + m * 1024 + g1 * 8);
                #pragma unroll
                for (int n = 0; n < 4; ++n) {
                    acc[m][n] = __builtin_amdgcn_mfma_f32_16x16x32_bf16(
                                    a0, bfr[n][0], acc[m][n], 0, 0, 0);
                    acc[m][n] = __builtin_amdgcn_mfma_f32_16x16x32_bf16(
                                    a1, bfr[n][1], acc[m][n], 0, 0, 0);
                }
            }
        }
        if (++kw == 3) { kw = 0; ++kh; }
    }

    #pragma unroll
    for (int m = 0; m < 4; ++m) {
        const int ocm = oc0 + wm0 + m * 16 + q_ * 4;
        float sc[4], sh[4];
        #pragma unroll
        for (int r = 0; r < 4; ++r) {
            sc[r] = P.bg[ocm + r] * rsqrtf(P.bv[ocm + r] + BN_EPS);
            sh[r] = P.bb[ocm + r] - P.bm[ocm + r] * sc[r];
        }
        #pragma unroll
        for (int n = 0; n < 4; ++n) {
            const int pg = p0 + wn0 + n * 16 + lr;
            if (pg < P.N) {
                unsigned e0 = f2bf(fmaxf(acc[m][n][0] * sc[0] + sh[0], 0.f));
                unsigned e1 = f2bf(fmaxf(acc[m][n][1] * sc[1] + sh[1], 0.f));
                unsigned e2 = f2bf(fmaxf(acc[m][n][2] * sc[2] + sh[2], 0.f));
                unsigned e3 = f2bf(fmaxf(acc[m][n][3] * sc[3] + sh[3], 0.f));
                uint2 v; v.x = e0 | (e1 << 16); v.y = e2 | (e3 << 16);
                *(uint2*)(P.out + (size_t)pg * 256 + ocm) = v;
            }
        }
    }
}

// ===========================================================================
// Fused xcorr + head:
//   phase X: depthwise xcorr for 64 positions of one batch -> X LDS [64][264]
//   GEMM1  : h1w(256x256) . X^T + BN + ReLU -> Y over X's LDS (same layout)
//   GEMM2  : h2w(16x256) . Y^T + bias -> out f32 [b][10][625]
// xcorr FMA order and all GEMM fragment/MFMA orders identical to round-7
// (values bitwise-identical). grid = 64 b x 10 pos-tiles = 640 blocks.
// ===========================================================================
__global__ __launch_bounds__(256)
void fused_xcorr_head_kernel(const unsigned short* __restrict__ sfeat,
                             const unsigned short* __restrict__ kfeat,
                             const unsigned short* __restrict__ h1w16,
                             const unsigned short* __restrict__ h2w16,
                             const float* __restrict__ bn_g,
                             const float* __restrict__ bn_b,
                             const float* __restrict__ bn_m,
                             const float* __restrict__ bn_v,
                             const float* __restrict__ h2b,
                             float* __restrict__ out)
{
    __shared__ __align__(16) unsigned short Alds[16384];     // [256][64] swizzled A
    __shared__ __align__(16) unsigned short Xlds[64 * 264];  // X tile, then Y tile

    const int tid  = threadIdx.x;
    const int lane = tid & 63;
    const int wid  = tid >> 6;
    const int bid  = blockIdx.x;
    const int b    = bid / 10;
    const int pt   = bid - b * 10;
    const int p0   = pt * 64;          // local position base within batch

    // ---- phase X: xcorr, thread = channel c, sliding window per oh row ----
    {
        const int c = tid;
        float kv[25];
        const unsigned short* kp = kfeat + (size_t)b * 25 * 256 + c;
        #pragma unroll
        for (int t = 0; t < 25; ++t) kv[t] = bf2f(kp[t * 256]);

        if (pt == 9) {          // tail tile: rows 49..63 invalid -> deterministic 0
            #pragma unroll
            for (int j = 49; j < 64; ++j) Xlds[j * 264 + c] = 0;
        }

        const int oh0 = p0 / 25;
        for (int ohr = 0; ohr < 4; ++ohr) {
            const int oh = oh0 + ohr;
            const int jbase = oh * 25 - p0;
            if (oh <= 24 && jbase < 64) {
                float acc[25];
                #pragma unroll
                for (int z = 0; z < 25; ++z) acc[z] = 0.f;
                const unsigned short* sp =
                    sfeat + ((size_t)(b * 29 + oh)) * 29 * 256 + c;
                #pragma unroll
                for (int i = 0; i < 5; ++i)
                    #pragma unroll
                    for (int w2 = 0; w2 < 29; ++w2) {
                        const float sv = bf2f(sp[(i * 29 + w2) * 256]);
                        #pragma unroll
                        for (int t = 0; t < 5; ++t) {
                            const int ww = w2 - t;
                            if (ww >= 0 && ww <= 24)
                                acc[ww] += sv * kv[i * 5 + t];
                        }
                    }
                #pragma unroll
                for (int ow = 0; ow < 25; ++ow) {
                    const int j = jbase + ow;
                    if (j >= 0 && j < 64)
                        Xlds[j * 264 + c] = f2bf(acc[ow]);
                }
            }
        }
    }

    // ---- GEMM1: A = h1w (GLDS-staged, swizzled), B = X tile in LDS ----
    const int lrow = lane >> 3;
    int aoffs[8], aldsr[8];
    #pragma unroll
    for (int s = 0; s < 8; ++s) {
        const int rowb = s * 32 + wid * 8;
        const int row  = rowb + lrow;
        const int g    = (lane & 7) ^ (row & 7);
        aoffs[s] = row * 256 + g * 8;
        aldsr[s] = rowb * 64;
    }
    const int q_ = lane >> 4;
    const int lr = lane & 15;
    const int wm = wid >> 1;
    const int wn = wid & 1;
    const int g0 = q_ ^ (lane & 7);
    const int g1 = (4 + q_) ^ (lane & 7);
    const unsigned short* Abase = &Alds[(wm * 128 + lr) * 64];

    f32x4 acc1[8][2] = {};

    for (int ics = 0; ics < 4; ++ics) {
        const int ic0 = ics * 64;
        __syncthreads();                 // ics=0: X writes visible; else: A reuse
        #pragma unroll
        for (int s = 0; s < 8; ++s)
            GLDS16(h1w16 + aoffs[s] + ic0, &Alds[aldsr[s]]);
        __syncthreads();

        bf16x8 bfr[2][2];
        #pragma unroll
        for (int n = 0; n < 2; ++n) {
            const int rowp = wn * 32 + n * 16 + lr;
            bfr[n][0] = *(const bf16x8*)(Xlds + rowp * 264 + ic0 + q_ * 8);
            bfr[n][1] = *(const bf16x8*)(Xlds + rowp * 264 + ic0 + 32 + q_ * 8);
        }
        #pragma unroll
        for (int m = 0; m < 8; ++m) {
            bf16x8 a0 = *(const bf16x8*)(Abase + m * 1024 + g0 * 8);
            bf16x8 a1 = *(const bf16x8*)(Abase + m * 1024 + g1 * 8);
            #pragma unroll
            for (int n = 0; n < 2; ++n) {
                acc1[m][n] = __builtin_amdgcn_mfma_f32_16x16x32_bf16(
                                 a0, bfr[n][0], acc1[m][n], 0, 0, 0);
                acc1[m][n] = __builtin_amdgcn_mfma_f32_16x16x32_bf16(
                                 a1, bfr[n][1], acc1[m][n], 0, 0, 0);
            }
        }
    }

    // ---- BN + ReLU -> Y tile over Xlds (same [64][264] layout) ----
    __syncthreads();
    #pragma unroll
    for (int m = 0; m < 8; ++m) {
        const int ocm = wm * 128 + m * 16 + q_ * 4;
        float sc[4], sh[4];
        #pragma unroll
        for (int r = 0; r < 4; ++r) {
            sc[r] = bn_g[ocm + r] * rsqrtf(bn_v[ocm + r] + BN_EPS);
            sh[r] = bn_b[ocm + r] - bn_m[ocm + r] * sc[r];
        }
        #pragma unroll
        for (int n = 0; n < 2; ++n) {
            const int pl = wn * 32 + n * 16 + lr;
            unsigned e0 = f2bf(fmaxf(acc1[m][n][0] * sc[0] + sh[0], 0.f));
            unsigned e1 = f2bf(fmaxf(acc1[m][n][1] * sc[1] + sh[1], 0.f));
            unsigned e2 = f2bf(fmaxf(acc1[m][n][2] * sc[2] + sh[2], 0.f));
            unsigned e3 = f2bf(fmaxf(acc1[m][n][3] * sc[3] + sh[3], 0.f));
            uint2 v; v.x = e0 | (e1 << 16); v.y = e2 | (e3 << 16);
            *(uint2*)(Xlds + (size_t)pl * 264 + ocm) = v;
        }
    }
    __syncthreads();

    // ---- GEMM2: out[16 oc][64 pos] = h2w16(16x256) . Y^T ----
    const int pl = wid * 16 + lr;
    const unsigned short* arow = h2w16 + lr * 256 + q_ * 8;
    const unsigned short* brow = Xlds + (size_t)pl * 264 + q_ * 8;

    f32x4 acc2 = {};
    #pragma unroll
    for (int ks = 0; ks < 8; ++ks) {
        bf16x8 a  = *(const bf16x8*)(arow + ks * 32);
        bf16x8 bb = *(const bf16x8*)(brow + ks * 32);
        acc2 = __builtin_amdgcn_mfma_f32_16x16x32_bf16(a, bb, acc2, 0, 0, 0);
    }

    const int plocal = p0 + pl;
    if (plocal < 625) {
        #pragma unroll
        for (int r = 0; r < 4; ++r) {
            const int oc = q_ * 4 + r;
            if (oc < 10)
                out[((size_t)(b * 10 + oc)) * 625 + plocal] = acc2[r] + h2b[oc];
        }
    }
}

// ===========================================================================
extern "C" void kernel_launch(void* const* d_in, const int* in_sizes, int n_in,
                              void* d_out, int out_size, void* d_ws, size_t ws_size,
                              hipStream_t stream)
{
    const float* kin  = (const float*)d_in[0];
    const float* srch = (const float*)d_in[1];
    const float* ck_w = (const float*)d_in[2];
    const float* ck_g = (const float*)d_in[3];
    const float* ck_b = (const float*)d_in[4];
    const float* ck_m = (const float*)d_in[5];
    const float* ck_v = (const float*)d_in[6];
    const float* cs_w = (const float*)d_in[7];
    const float* cs_g = (const float*)d_in[8];
    const float* cs_b = (const float*)d_in[9];
    const float* cs_m = (const float*)d_in[10];
    const float* cs_v = (const float*)d_in[11];
    const float* h1_w = (const float*)d_in[12];
    const float* h_g  = (const float*)d_in[13];
    const float* h_b  = (const float*)d_in[14];
    const float* h_m  = (const float*)d_in[15];
    const float* h_v  = (const float*)d_in[16];
    const float* h2_w = (const float*)d_in[17];
    const float* h2_b = (const float*)d_in[18];

    const int B = in_sizes[0] / (256 * 7 * 7);   // 64

    // ---- workspace layout (lifetime-aliased) ----
    uint8_t* w = (uint8_t*)d_ws;
    unsigned short* s16     = (unsigned short*)(w);             // B*31*31*256 bf16
    unsigned short* sfeat16 = (unsigned short*)(w + 31490048);  // B*841*256 bf16
    unsigned short* kf16    = (unsigned short*)(w + 59047936);  // B*25*256 bf16
    unsigned short* k16     = (unsigned short*)(w + 59867136);  // B*7*7*256 bf16
    unsigned short* wTk     = (unsigned short*)(w + 61472768);
    unsigned short* wTs     = (unsigned short*)(w + 62652416);
    unsigned short* h1w16   = (unsigned short*)(w + 63832064);
    unsigned short* h2w16   = (unsigned short*)(w + 63963136);

    const int Ns = B * 841;    // 53824
    const int Nk = B * 25;     // 1600
    const int Gs = 2 * ((Ns + 127) / 128);   // 842
    const int Gk = 2 * ((Nk + 127) / 128);   // 26
    const int GS = B * 16 * 4;               // 4096 search-transpose blocks
    const int GK = B * 1 * 4;                // 256 kernel-transpose blocks

    dim3 blk(256, 1, 1);

    // 1) prep: tiled-transpose NHWC + weight conversions
    hipLaunchKernelGGL(prep_kernel, dim3(GS + GK + 4880), blk, 0, stream,
                       srch, kin, cs_w, ck_w, h1_w, h2_w,
                       s16, k16, wTs, wTk, h1w16, h2w16, GS, GK);

    // 2) both 3x3 convs (unchanged)
    ConvParams S{ s16, wTs, cs_g, cs_b, cs_m, cs_v, sfeat16, 31, 31, 29, 841, Ns };
    ConvParams K{ k16, wTk, ck_g, ck_b, ck_m, ck_v, kf16, 7, 7, 5, 25, Nk };
    hipLaunchKernelGGL(conv3x3_kernel, dim3(Gs + Gk), blk, 0, stream, S, K, Gs);

    // 3) fused xcorr + head -> d_out
    hipLaunchKernelGGL(fused_xcorr_head_kernel, dim3(B * 10), blk, 0, stream,
                       sfeat16, kf16, h1w16, h2w16,
                       h_g, h_b, h_m, h_v, h2_b, (float*)d_out);
}